// Round 2
// baseline (798.513 us; speedup 1.0000x reference)
//
#include <hip/hip_runtime.h>

typedef unsigned short ushort_t;
typedef short bf16x8 __attribute__((ext_vector_type(8)));
typedef float f32x4 __attribute__((ext_vector_type(4)));

__device__ __forceinline__ float bf2f(ushort_t u) {
    union { unsigned int i; float f; } v; v.i = ((unsigned int)u) << 16; return v.f;
}
__device__ __forceinline__ ushort_t f2bf(float f) {
    union { float f; unsigned int i; } v; v.f = f;
    unsigned int u = v.i;
    unsigned int r = (u + 0x7FFFu + ((u >> 16) & 1u)) >> 16;
    return (ushort_t)r;
}
__device__ __forceinline__ float hsum4(f32x4 v) { return (v[0] + v[1]) + (v[2] + v[3]); }

// ---------------- fc_W -> bf16 (vectorized) ----------------
__global__ void k_convert(const float* __restrict__ w, ushort_t* __restrict__ o, int n4) {
    int i = blockIdx.x * blockDim.x + threadIdx.x;
    if (i < n4) {
        f32x4 v = ((const f32x4*)w)[i];
        ushort_t r0 = f2bf(v[0]), r1 = f2bf(v[1]), r2 = f2bf(v[2]), r3 = f2bf(v[3]);
        union { ushort_t u[4]; unsigned long long q; } p;
        p.u[0] = r0; p.u[1] = r1; p.u[2] = r2; p.u[3] = r3;
        ((unsigned long long*)o)[i] = p.q;
    }
}

// ---------------- encoder GRU: one block per sentence s ----------------
__global__ __launch_bounds__(384, 1) void k_encoder(
    const int* __restrict__ doc, const float* __restrict__ emb,
    const float* __restrict__ Wih, const float* __restrict__ Whh,
    const float* __restrict__ bih, const float* __restrict__ bhh,
    float* __restrict__ sent) {
    int s = blockIdx.x, j = threadIdx.x;
    __shared__ f32x4 x4[16], h4[32];
    __shared__ float gi[384], gh[384];
    float* x = (float*)x4;
    float* h = (float*)h4;
    f32x4 wih[16], whh[32];
#pragma unroll
    for (int k = 0; k < 16; k++) wih[k] = *(const f32x4*)(Wih + j * 64 + k * 4);
#pragma unroll
    for (int k = 0; k < 32; k++) whh[k] = *(const f32x4*)(Whh + j * 128 + k * 4);
    float bi = bih[j], bh = bhh[j];
    if (j < 128) h[j] = 0.f;
    __syncthreads();
    for (int t = 0; t < 48; t++) {
        if (j < 64) { int tok = doc[s * 48 + t]; x[j] = emb[tok * 64 + j]; }
        __syncthreads();
        f32x4 a0 = {0,0,0,0}, a1 = {0,0,0,0}, b0 = {0,0,0,0}, b1 = {0,0,0,0};
#pragma unroll
        for (int k = 0; k < 16; k += 2) { a0 += wih[k] * x4[k]; a1 += wih[k+1] * x4[k+1]; }
#pragma unroll
        for (int k = 0; k < 32; k += 2) { b0 += whh[k] * h4[k]; b1 += whh[k+1] * h4[k+1]; }
        gi[j] = bi + hsum4(a0 + a1); gh[j] = bh + hsum4(b0 + b1);
        __syncthreads();
        if (j < 128) {
            float r = 1.f / (1.f + __expf(-(gi[j] + gh[j])));
            float z = 1.f / (1.f + __expf(-(gi[j + 128] + gh[j + 128])));
            float n = tanhf(gi[j + 256] + r * gh[j + 256]);
            h[j] = (1.f - z) * n + z * h[j];
        }
        __syncthreads();
    }
    if (j < 128) sent[s * 128 + j] = h[j];
}

// ---------------- doc-GRU input gates (parallel over steps) ----------------
__global__ void k_doc_gi(const float* __restrict__ sv, const float* __restrict__ Wih,
                         const float* __restrict__ bih, float* __restrict__ gidoc) {
    int i = blockIdx.x, j = threadIdx.x;
    __shared__ f32x4 v4[32];
    if (j < 128) ((float*)v4)[j] = sv[i * 128 + j];
    __syncthreads();
    f32x4 a0 = {0,0,0,0}, a1 = {0,0,0,0};
#pragma unroll
    for (int k = 0; k < 32; k += 2) {
        a0 += *(const f32x4*)(Wih + j * 128 + k * 4) * v4[k];
        a1 += *(const f32x4*)(Wih + j * 128 + (k + 1) * 4) * v4[k + 1];
    }
    gidoc[i * 384 + j] = bih[j] + hsum4(a0 + a1);
}

// ---------------- doc GRU: single block, 128 sequential steps ----------------
__global__ __launch_bounds__(384, 1) void k_doc_seq(
    const float* __restrict__ gidoc, const float* __restrict__ Whh,
    const float* __restrict__ bhh, float* __restrict__ dvec) {
    int j = threadIdx.x;
    __shared__ f32x4 h4[32];
    __shared__ float gi[384], gh[384];
    float* h = (float*)h4;
    f32x4 whh[32];
#pragma unroll
    for (int k = 0; k < 32; k++) whh[k] = *(const f32x4*)(Whh + j * 128 + k * 4);
    float bh = bhh[j];
    if (j < 128) h[j] = 0.f;
    __syncthreads();
    for (int i = 0; i < 128; i++) {
        float gval = gidoc[i * 384 + j];
        f32x4 b0 = {0,0,0,0}, b1 = {0,0,0,0};
#pragma unroll
        for (int k = 0; k < 32; k += 2) { b0 += whh[k] * h4[k]; b1 += whh[k+1] * h4[k+1]; }
        gh[j] = bh + hsum4(b0 + b1); gi[j] = gval;
        __syncthreads();
        if (j < 128) {
            float r = 1.f / (1.f + __expf(-(gi[j] + gh[j])));
            float z = 1.f / (1.f + __expf(-(gi[j + 128] + gh[j + 128])));
            float n = tanhf(gi[j + 256] + r * gh[j + 256]);
            h[j] = (1.f - z) * n + z * h[j];
        }
        __syncthreads();
    }
    if (j < 128) dvec[j] = h[j];
}

// ---------------- decoder context gate vector ----------------
__global__ void k_gctx(const float* __restrict__ Wih, const float* __restrict__ bih,
                       const float* __restrict__ dvec, float* __restrict__ gctx) {
    int j = threadIdx.x;
    __shared__ f32x4 v4[32];
    if (j < 128) ((float*)v4)[j] = dvec[j];
    __syncthreads();
    f32x4 a0 = {0,0,0,0}, a1 = {0,0,0,0};
#pragma unroll
    for (int k = 0; k < 32; k += 2) {
        a0 += *(const f32x4*)(Wih + j * 192 + 64 + k * 4) * v4[k];
        a1 += *(const f32x4*)(Wih + j * 192 + 64 + (k + 1) * 4) * v4[k + 1];
    }
    gctx[j] = bih[j] + hsum4(a0 + a1);
}

// ---------------- decoder input gates (parallel over s,t) ----------------
__global__ __launch_bounds__(384, 1) void k_dec_gi(
    const int* __restrict__ doc, const float* __restrict__ emb,
    const float* __restrict__ Wih, const float* __restrict__ gctx,
    float* __restrict__ gidec) {
    int s = blockIdx.x, j = threadIdx.x;
    __shared__ f32x4 x4[16];
    float* x = (float*)x4;
    f32x4 wih[16];
#pragma unroll
    for (int k = 0; k < 16; k++) wih[k] = *(const f32x4*)(Wih + j * 192 + k * 4);
    float g = gctx[j];
    for (int t = 0; t < 47; t++) {
        __syncthreads();
        if (j < 64) { int tok = doc[s * 48 + t]; x[j] = emb[tok * 64 + j]; }
        __syncthreads();
        f32x4 a0 = {0,0,0,0}, a1 = {0,0,0,0};
#pragma unroll
        for (int k = 0; k < 16; k += 2) { a0 += wih[k] * x4[k]; a1 += wih[k+1] * x4[k+1]; }
        gidec[(t * 128 + s) * 384 + j] = g + hsum4(a0 + a1);
    }
}

// ---------------- decoder GRU: one block per sentence, stores h2 (bf16) ----------------
__global__ __launch_bounds__(384, 1) void k_dec_seq(
    const float* __restrict__ gidec, const float* __restrict__ Whh,
    const float* __restrict__ bhh, const float* __restrict__ sent,
    ushort_t* __restrict__ h2b) {
    int s = blockIdx.x, j = threadIdx.x;
    __shared__ f32x4 h4[32];
    __shared__ float gi[384], gh[384];
    float* h = (float*)h4;
    f32x4 whh[32];
#pragma unroll
    for (int k = 0; k < 32; k++) whh[k] = *(const f32x4*)(Whh + j * 128 + k * 4);
    float bh = bhh[j];
    if (j < 128) h[j] = sent[s * 128 + j];
    __syncthreads();
    for (int t = 0; t < 47; t++) {
        float gval = gidec[(t * 128 + s) * 384 + j];
        f32x4 b0 = {0,0,0,0}, b1 = {0,0,0,0};
#pragma unroll
        for (int k = 0; k < 32; k += 2) { b0 += whh[k] * h4[k]; b1 += whh[k+1] * h4[k+1]; }
        gh[j] = bh + hsum4(b0 + b1); gi[j] = gval;
        __syncthreads();
        if (j < 128) {
            float r = 1.f / (1.f + __expf(-(gi[j] + gh[j])));
            float z = 1.f / (1.f + __expf(-(gi[j + 128] + gh[j + 128])));
            float n = tanhf(gi[j + 256] + r * gh[j + 256]);
            float hn = (1.f - z) * n + z * h[j];
            h[j] = hn;
            h2b[(t * 128 + s) * 128 + j] = f2bf(hn);
        }
        __syncthreads();
    }
}

// ---------------- target logits (one wave per row) ----------------
__global__ void k_tl(const int* __restrict__ doc, const ushort_t* __restrict__ h2b,
                     const ushort_t* __restrict__ wb, const float* __restrict__ fcb,
                     float* __restrict__ tl) {
    int r = blockIdx.x * 4 + (threadIdx.x >> 6);
    int lane = threadIdx.x & 63;
    int s = r & 127, t = r >> 7;
    int tok = doc[s * 48 + t + 1];
    const ushort_t* hp = h2b + r * 128;
    const ushort_t* wp = wb + tok * 128;
    float acc = bf2f(hp[lane]) * bf2f(wp[lane]) + bf2f(hp[lane + 64]) * bf2f(wp[lane + 64]);
#pragma unroll
    for (int m = 32; m >= 1; m >>= 1) acc += __shfl_xor(acc, m);
    if (lane == 0) tl[r] = acc + fcb[tok];
}

// ---------------- fused logits GEMM + sum(exp), LDS-staged 2-phase pipeline ----------------
// grid: 47 rowblocks x 20 v-chunks (1600 cols each, 25 tiles of 64).
// block 512 = 8 waves: 2 row-groups x 4 col-groups; wave computes 64 rows x 16 cols/tile.
#define LSE_VC 20
#define LSE_NC 1600
#define LSE_NT 25
__global__ __launch_bounds__(512, 4) void k_lse(
    const ushort_t* __restrict__ h2b, const ushort_t* __restrict__ wb,
    const float* __restrict__ fcb, float* __restrict__ parts) {
    int rb = blockIdx.x / LSE_VC;
    int vc = blockIdx.x % LSE_VC;
    int t = threadIdx.x;
    int wave = t >> 6, lane = t & 63;
    int rg = wave >> 2, cg = wave & 3;
    int q = lane >> 4, l15 = lane & 15;

    __shared__ __align__(16) char ldsB[32768];  // 2 x 16KB B tile

    // A fragments: 64 rows x K=128 per wave, register-resident
    int row0 = rb * 128 + rg * 64;
    bf16x8 a[4][4];
    const ushort_t* ap = h2b + (size_t)(row0 + l15) * 128 + q * 8;
#pragma unroll
    for (int m = 0; m < 4; m++)
#pragma unroll
        for (int c = 0; c < 4; c++) a[m][c] = *(const bf16x8*)(ap + m * 2048 + c * 32);

    // staging: source offset (inverse-swizzled), LDS dest linear
    const char* wbB = (const char*)wb;
    int so = ((t >> 4) << 8) + (((t & 15) ^ ((t >> 4) & 15)) << 4);
    char* dst1 = ldsB + wave * 1024;

#define LSE_STAGE(buf, cb) do { \
    const char* g_ = wbB + (size_t)(cb) * 256 + so; \
    char* d_ = dst1 + (buf) * 16384; \
    __builtin_amdgcn_global_load_lds((const __attribute__((address_space(1))) unsigned int*)(g_), \
                                     (__attribute__((address_space(3))) unsigned int*)(d_), 16, 0, 0); \
    __builtin_amdgcn_global_load_lds((const __attribute__((address_space(1))) unsigned int*)(g_ + 8192), \
                                     (__attribute__((address_space(3))) unsigned int*)(d_ + 8192), 16, 0, 0); \
} while (0)

    // swizzled read offsets within a 16KB tile
    int col_local = cg * 16 + l15;
    int ra[4];
#pragma unroll
    for (int c = 0; c < 4; c++) ra[c] = col_local * 256 + ((q * 16 + c * 64) ^ (l15 << 4));

    int cb0 = vc * LSE_NC;
    f32x4 se[4] = {{0,0,0,0},{0,0,0,0},{0,0,0,0},{0,0,0,0}};

    LSE_STAGE(0, cb0);
    __syncthreads();
    int cur = 0;
    for (int tile = 0; tile < LSE_NT; ++tile) {
        if (tile + 1 < LSE_NT) LSE_STAGE(cur ^ 1, cb0 + (tile + 1) * 64);
        const char* bb = ldsB + (cur << 14);
        float bias = fcb[cb0 + tile * 64 + col_local];
        f32x4 acc[4] = {{0,0,0,0},{0,0,0,0},{0,0,0,0},{0,0,0,0}};
#pragma unroll
        for (int c = 0; c < 4; c++) {
            bf16x8 b = *(const bf16x8*)(bb + ra[c]);
#pragma unroll
            for (int m = 0; m < 4; m++)
                acc[m] = __builtin_amdgcn_mfma_f32_16x16x32_bf16(a[m][c], b, acc[m], 0, 0, 0);
        }
#pragma unroll
        for (int m = 0; m < 4; m++) {
            se[m][0] += __expf(acc[m][0] + bias);
            se[m][1] += __expf(acc[m][1] + bias);
            se[m][2] += __expf(acc[m][2] + bias);
            se[m][3] += __expf(acc[m][3] + bias);
        }
        __syncthreads();
        cur ^= 1;
    }

    // reduce over the 16 cols held by lanes (l15) and store per (vc,cg) partial
#pragma unroll
    for (int m = 0; m < 4; m++) {
        f32x4 v = se[m];
#pragma unroll
        for (int d = 1; d < 16; d <<= 1) {
            v[0] += __shfl_xor(v[0], d);
            v[1] += __shfl_xor(v[1], d);
            v[2] += __shfl_xor(v[2], d);
            v[3] += __shfl_xor(v[3], d);
        }
        if (l15 == 0) {
            float* p = parts + (size_t)(vc * 4 + cg) * 6016 + row0 + m * 16 + q * 4;
            p[0] = v[0]; p[1] = v[1]; p[2] = v[2]; p[3] = v[3];
        }
    }
}

// ---------------- final reduction ----------------
__global__ void k_final(const float* __restrict__ parts, const float* __restrict__ tl,
                        float* __restrict__ out) {
    __shared__ float red[1024];
    int tid = threadIdx.x;
    float acc = 0.f;
    for (int r = tid; r < 6016; r += 1024) {
        float tot = 0.f;
        for (int c = 0; c < 80; c++) tot += parts[(size_t)c * 6016 + r];
        acc += logf(tot) - tl[r];
    }
    red[tid] = acc;
    __syncthreads();
    for (int s = 512; s > 0; s >>= 1) {
        if (tid < s) red[tid] += red[tid + s];
        __syncthreads();
    }
    if (tid == 0) out[0] = red[0] / 6016.f;
}

extern "C" void kernel_launch(void* const* d_in, const int* in_sizes, int n_in,
                              void* d_out, int out_size, void* d_ws, size_t ws_size,
                              hipStream_t stream) {
    const int* doc = (const int*)d_in[0];
    const float* enc_emb = (const float*)d_in[1];
    const float* enc_Wih = (const float*)d_in[2];
    const float* enc_Whh = (const float*)d_in[3];
    const float* enc_bih = (const float*)d_in[4];
    const float* enc_bhh = (const float*)d_in[5];
    const float* doc_Wih = (const float*)d_in[6];
    const float* doc_Whh = (const float*)d_in[7];
    const float* doc_bih = (const float*)d_in[8];
    const float* doc_bhh = (const float*)d_in[9];
    const float* dec_emb = (const float*)d_in[10];
    const float* dec_Wih = (const float*)d_in[11];
    const float* dec_Whh = (const float*)d_in[12];
    const float* dec_bih = (const float*)d_in[13];
    const float* dec_bhh = (const float*)d_in[14];
    const float* fc_W = (const float*)d_in[15];
    const float* fc_b = (const float*)d_in[16];

    char* ws = (char*)d_ws;
    ushort_t* fcWb = (ushort_t*)(ws + 0);            // 8,192,000 B
    float* sent    = (float*)(ws + 8192000);         // 65,536 B
    float* dvec    = (float*)(ws + 8257536);         // 512 B
    float* gidoc   = (float*)(ws + 8258048);         // 196,608 B
    float* gctx    = (float*)(ws + 8454656);         // 1,536 B
    float* gidec   = (float*)(ws + 8456192);         // 9,240,576 B
    ushort_t* h2b  = (ushort_t*)(ws + 17696768);     // 1,540,096 B
    float* tl      = (float*)(ws + 19236864);        // 24,064 B
    float* parts   = (float*)(ws + 19260928);        // 80*6016*4 = 1,925,120 B
    float* out = (float*)d_out;

    k_convert<<<4000, 256, 0, stream>>>(fc_W, fcWb, 1024000);
    k_encoder<<<128, 384, 0, stream>>>(doc, enc_emb, enc_Wih, enc_Whh, enc_bih, enc_bhh, sent);
    k_doc_gi<<<128, 384, 0, stream>>>(sent, doc_Wih, doc_bih, gidoc);
    k_doc_seq<<<1, 384, 0, stream>>>(gidoc, doc_Whh, doc_bhh, dvec);
    k_gctx<<<1, 384, 0, stream>>>(dec_Wih, dec_bih, dvec, gctx);
    k_dec_gi<<<128, 384, 0, stream>>>(doc, dec_emb, dec_Wih, gctx, gidec);
    k_dec_seq<<<128, 384, 0, stream>>>(gidec, dec_Whh, dec_bhh, sent, h2b);
    k_tl<<<1504, 256, 0, stream>>>(doc, h2b, fcWb, fc_b, tl);
    k_lse<<<47 * LSE_VC, 512, 0, stream>>>(h2b, fcWb, fc_b, parts);
    k_final<<<1, 1024, 0, stream>>>(parts, tl, out);
}

// Round 3
// 509.446 us; speedup vs baseline: 1.5674x; 1.5674x over previous
//
#include <hip/hip_runtime.h>

typedef unsigned short ushort_t;
typedef short bf16x8 __attribute__((ext_vector_type(8)));
typedef float f32x4 __attribute__((ext_vector_type(4)));

__device__ __forceinline__ float bf2f(ushort_t u) {
    union { unsigned int i; float f; } v; v.i = ((unsigned int)u) << 16; return v.f;
}
__device__ __forceinline__ ushort_t f2bf(float f) {
    union { float f; unsigned int i; } v; v.f = f;
    unsigned int u = v.i;
    unsigned int r = (u + 0x7FFFu + ((u >> 16) & 1u)) >> 16;
    return (ushort_t)r;
}
__device__ __forceinline__ float hsum4(f32x4 v) { return (v[0] + v[1]) + (v[2] + v[3]); }

// ---------------- fc_W -> bf16 (vectorized) ----------------
__global__ void k_convert(const float* __restrict__ w, ushort_t* __restrict__ o, int n4) {
    int i = blockIdx.x * blockDim.x + threadIdx.x;
    if (i < n4) {
        f32x4 v = ((const f32x4*)w)[i];
        ushort_t r0 = f2bf(v[0]), r1 = f2bf(v[1]), r2 = f2bf(v[2]), r3 = f2bf(v[3]);
        union { ushort_t u[4]; unsigned long long q; } p;
        p.u[0] = r0; p.u[1] = r1; p.u[2] = r2; p.u[3] = r3;
        ((unsigned long long*)o)[i] = p.q;
    }
}

// ---------------- encoder GRU: one block per sentence s ----------------
__global__ __launch_bounds__(384, 1) void k_encoder(
    const int* __restrict__ doc, const float* __restrict__ emb,
    const float* __restrict__ Wih, const float* __restrict__ Whh,
    const float* __restrict__ bih, const float* __restrict__ bhh,
    float* __restrict__ sent) {
    int s = blockIdx.x, j = threadIdx.x;
    __shared__ f32x4 x4[16], h4[32];
    __shared__ float gi[384], gh[384];
    float* x = (float*)x4;
    float* h = (float*)h4;
    f32x4 wih[16], whh[32];
#pragma unroll
    for (int k = 0; k < 16; k++) wih[k] = *(const f32x4*)(Wih + j * 64 + k * 4);
#pragma unroll
    for (int k = 0; k < 32; k++) whh[k] = *(const f32x4*)(Whh + j * 128 + k * 4);
    float bi = bih[j], bh = bhh[j];
    if (j < 128) h[j] = 0.f;
    __syncthreads();
    for (int t = 0; t < 48; t++) {
        if (j < 64) { int tok = doc[s * 48 + t]; x[j] = emb[tok * 64 + j]; }
        __syncthreads();
        f32x4 a0 = {0,0,0,0}, a1 = {0,0,0,0}, b0 = {0,0,0,0}, b1 = {0,0,0,0};
#pragma unroll
        for (int k = 0; k < 16; k += 2) { a0 += wih[k] * x4[k]; a1 += wih[k+1] * x4[k+1]; }
#pragma unroll
        for (int k = 0; k < 32; k += 2) { b0 += whh[k] * h4[k]; b1 += whh[k+1] * h4[k+1]; }
        gi[j] = bi + hsum4(a0 + a1); gh[j] = bh + hsum4(b0 + b1);
        __syncthreads();
        if (j < 128) {
            float r = 1.f / (1.f + __expf(-(gi[j] + gh[j])));
            float z = 1.f / (1.f + __expf(-(gi[j + 128] + gh[j + 128])));
            float n = tanhf(gi[j + 256] + r * gh[j + 256]);
            h[j] = (1.f - z) * n + z * h[j];
        }
        __syncthreads();
    }
    if (j < 128) sent[s * 128 + j] = h[j];
}

// ---------------- doc-GRU input gates (parallel over steps) ----------------
__global__ void k_doc_gi(const float* __restrict__ sv, const float* __restrict__ Wih,
                         const float* __restrict__ bih, float* __restrict__ gidoc) {
    int i = blockIdx.x, j = threadIdx.x;
    __shared__ f32x4 v4[32];
    if (j < 128) ((float*)v4)[j] = sv[i * 128 + j];
    __syncthreads();
    f32x4 a0 = {0,0,0,0}, a1 = {0,0,0,0};
#pragma unroll
    for (int k = 0; k < 32; k += 2) {
        a0 += *(const f32x4*)(Wih + j * 128 + k * 4) * v4[k];
        a1 += *(const f32x4*)(Wih + j * 128 + (k + 1) * 4) * v4[k + 1];
    }
    gidoc[i * 384 + j] = bih[j] + hsum4(a0 + a1);
}

// ---------------- doc GRU: single block, 128 sequential steps ----------------
__global__ __launch_bounds__(384, 1) void k_doc_seq(
    const float* __restrict__ gidoc, const float* __restrict__ Whh,
    const float* __restrict__ bhh, float* __restrict__ dvec) {
    int j = threadIdx.x;
    __shared__ f32x4 h4[32];
    __shared__ float gi[384], gh[384];
    float* h = (float*)h4;
    f32x4 whh[32];
#pragma unroll
    for (int k = 0; k < 32; k++) whh[k] = *(const f32x4*)(Whh + j * 128 + k * 4);
    float bh = bhh[j];
    if (j < 128) h[j] = 0.f;
    __syncthreads();
    for (int i = 0; i < 128; i++) {
        float gval = gidoc[i * 384 + j];
        f32x4 b0 = {0,0,0,0}, b1 = {0,0,0,0};
#pragma unroll
        for (int k = 0; k < 32; k += 2) { b0 += whh[k] * h4[k]; b1 += whh[k+1] * h4[k+1]; }
        gh[j] = bh + hsum4(b0 + b1); gi[j] = gval;
        __syncthreads();
        if (j < 128) {
            float r = 1.f / (1.f + __expf(-(gi[j] + gh[j])));
            float z = 1.f / (1.f + __expf(-(gi[j + 128] + gh[j + 128])));
            float n = tanhf(gi[j + 256] + r * gh[j + 256]);
            h[j] = (1.f - z) * n + z * h[j];
        }
        __syncthreads();
    }
    if (j < 128) dvec[j] = h[j];
}

// ---------------- decoder context gate vector ----------------
__global__ void k_gctx(const float* __restrict__ Wih, const float* __restrict__ bih,
                       const float* __restrict__ dvec, float* __restrict__ gctx) {
    int j = threadIdx.x;
    __shared__ f32x4 v4[32];
    if (j < 128) ((float*)v4)[j] = dvec[j];
    __syncthreads();
    f32x4 a0 = {0,0,0,0}, a1 = {0,0,0,0};
#pragma unroll
    for (int k = 0; k < 32; k += 2) {
        a0 += *(const f32x4*)(Wih + j * 192 + 64 + k * 4) * v4[k];
        a1 += *(const f32x4*)(Wih + j * 192 + 64 + (k + 1) * 4) * v4[k + 1];
    }
    gctx[j] = bih[j] + hsum4(a0 + a1);
}

// ---------------- decoder input gates (parallel over s,t) ----------------
__global__ __launch_bounds__(384, 1) void k_dec_gi(
    const int* __restrict__ doc, const float* __restrict__ emb,
    const float* __restrict__ Wih, const float* __restrict__ gctx,
    float* __restrict__ gidec) {
    int s = blockIdx.x, j = threadIdx.x;
    __shared__ f32x4 x4[16];
    float* x = (float*)x4;
    f32x4 wih[16];
#pragma unroll
    for (int k = 0; k < 16; k++) wih[k] = *(const f32x4*)(Wih + j * 192 + k * 4);
    float g = gctx[j];
    for (int t = 0; t < 47; t++) {
        __syncthreads();
        if (j < 64) { int tok = doc[s * 48 + t]; x[j] = emb[tok * 64 + j]; }
        __syncthreads();
        f32x4 a0 = {0,0,0,0}, a1 = {0,0,0,0};
#pragma unroll
        for (int k = 0; k < 16; k += 2) { a0 += wih[k] * x4[k]; a1 += wih[k+1] * x4[k+1]; }
        gidec[(t * 128 + s) * 384 + j] = g + hsum4(a0 + a1);
    }
}

// ---------------- decoder GRU: one block per sentence, stores h2 (bf16) ----------------
__global__ __launch_bounds__(384, 1) void k_dec_seq(
    const float* __restrict__ gidec, const float* __restrict__ Whh,
    const float* __restrict__ bhh, const float* __restrict__ sent,
    ushort_t* __restrict__ h2b) {
    int s = blockIdx.x, j = threadIdx.x;
    __shared__ f32x4 h4[32];
    __shared__ float gi[384], gh[384];
    float* h = (float*)h4;
    f32x4 whh[32];
#pragma unroll
    for (int k = 0; k < 32; k++) whh[k] = *(const f32x4*)(Whh + j * 128 + k * 4);
    float bh = bhh[j];
    if (j < 128) h[j] = sent[s * 128 + j];
    __syncthreads();
    for (int t = 0; t < 47; t++) {
        float gval = gidec[(t * 128 + s) * 384 + j];
        f32x4 b0 = {0,0,0,0}, b1 = {0,0,0,0};
#pragma unroll
        for (int k = 0; k < 32; k += 2) { b0 += whh[k] * h4[k]; b1 += whh[k+1] * h4[k+1]; }
        gh[j] = bh + hsum4(b0 + b1); gi[j] = gval;
        __syncthreads();
        if (j < 128) {
            float r = 1.f / (1.f + __expf(-(gi[j] + gh[j])));
            float z = 1.f / (1.f + __expf(-(gi[j + 128] + gh[j + 128])));
            float n = tanhf(gi[j + 256] + r * gh[j + 256]);
            float hn = (1.f - z) * n + z * h[j];
            h[j] = hn;
            h2b[(t * 128 + s) * 128 + j] = f2bf(hn);
        }
        __syncthreads();
    }
}

// ---------------- target logits (one wave per row) ----------------
__global__ void k_tl(const int* __restrict__ doc, const ushort_t* __restrict__ h2b,
                     const ushort_t* __restrict__ wb, const float* __restrict__ fcb,
                     float* __restrict__ tl) {
    int r = blockIdx.x * 4 + (threadIdx.x >> 6);
    int lane = threadIdx.x & 63;
    int s = r & 127, t = r >> 7;
    int tok = doc[s * 48 + t + 1];
    const ushort_t* hp = h2b + r * 128;
    const ushort_t* wp = wb + tok * 128;
    float acc = bf2f(hp[lane]) * bf2f(wp[lane]) + bf2f(hp[lane + 64]) * bf2f(wp[lane + 64]);
#pragma unroll
    for (int m = 32; m >= 1; m >>= 1) acc += __shfl_xor(acc, m);
    if (lane == 0) tl[r] = acc + fcb[tok];
}

// ---------------- fused logits GEMM + sum(exp), LDS-staged 2-phase pipeline ----------------
// grid: 47 rowblocks x 20 v-chunks (1600 cols each, 25 tiles of 64).
// block 512 = 8 waves: 2 row-groups x 4 col-groups; wave computes 64 rows x 16 cols/tile.
// launch_bounds(512,2): 256-VGPR budget — round-2's (512,4) capped at 64 VGPRs and
// spilled the se[] accumulators (793 MB of scratch writebacks, MfmaUtil 4%).
#define LSE_VC 20
#define LSE_NC 1600
#define LSE_NT 25
__global__ __launch_bounds__(512, 2) void k_lse(
    const ushort_t* __restrict__ h2b, const ushort_t* __restrict__ wb,
    const float* __restrict__ fcb, float* __restrict__ parts) {
    int rb = blockIdx.x / LSE_VC;
    int vc = blockIdx.x % LSE_VC;
    int t = threadIdx.x;
    int wave = t >> 6, lane = t & 63;
    int rg = wave >> 2, cg = wave & 3;
    int q = lane >> 4, l15 = lane & 15;

    __shared__ __align__(16) char ldsB[32768];  // 2 x 16KB B tile

    // A fragments: 64 rows x K=128 per wave, register-resident
    int row0 = rb * 128 + rg * 64;
    bf16x8 a[4][4];
    const ushort_t* ap = h2b + (size_t)(row0 + l15) * 128 + q * 8;
#pragma unroll
    for (int m = 0; m < 4; m++)
#pragma unroll
        for (int c = 0; c < 4; c++) a[m][c] = *(const bf16x8*)(ap + m * 2048 + c * 32);

    // staging: source offset (inverse-swizzled), LDS dest linear
    const char* wbB = (const char*)wb;
    int so = ((t >> 4) << 8) + (((t & 15) ^ ((t >> 4) & 15)) << 4);
    char* dst1 = ldsB + wave * 1024;

#define LSE_STAGE(buf, cb) do { \
    const char* g_ = wbB + (size_t)(cb) * 256 + so; \
    char* d_ = dst1 + (buf) * 16384; \
    __builtin_amdgcn_global_load_lds((const __attribute__((address_space(1))) unsigned int*)(g_), \
                                     (__attribute__((address_space(3))) unsigned int*)(d_), 16, 0, 0); \
    __builtin_amdgcn_global_load_lds((const __attribute__((address_space(1))) unsigned int*)(g_ + 8192), \
                                     (__attribute__((address_space(3))) unsigned int*)(d_ + 8192), 16, 0, 0); \
} while (0)

    // swizzled read offsets within a 16KB tile
    int col_local = cg * 16 + l15;
    int ra[4];
#pragma unroll
    for (int c = 0; c < 4; c++) ra[c] = col_local * 256 + ((q * 16 + c * 64) ^ (l15 << 4));

    int cb0 = vc * LSE_NC;
    f32x4 se[4] = {{0,0,0,0},{0,0,0,0},{0,0,0,0},{0,0,0,0}};

    LSE_STAGE(0, cb0);
    __syncthreads();
    int cur = 0;
    for (int tile = 0; tile < LSE_NT; ++tile) {
        if (tile + 1 < LSE_NT) LSE_STAGE(cur ^ 1, cb0 + (tile + 1) * 64);
        const char* bb = ldsB + (cur << 14);
        float bias = fcb[cb0 + tile * 64 + col_local];
        f32x4 acc[4] = {{0,0,0,0},{0,0,0,0},{0,0,0,0},{0,0,0,0}};
#pragma unroll
        for (int c = 0; c < 4; c++) {
            bf16x8 b = *(const bf16x8*)(bb + ra[c]);
#pragma unroll
            for (int m = 0; m < 4; m++)
                acc[m] = __builtin_amdgcn_mfma_f32_16x16x32_bf16(a[m][c], b, acc[m], 0, 0, 0);
        }
#pragma unroll
        for (int m = 0; m < 4; m++) {
            se[m][0] += __expf(acc[m][0] + bias);
            se[m][1] += __expf(acc[m][1] + bias);
            se[m][2] += __expf(acc[m][2] + bias);
            se[m][3] += __expf(acc[m][3] + bias);
        }
        __syncthreads();
        cur ^= 1;
    }

    // reduce over the 16 cols held by lanes (l15) and store per (vc,cg) partial
#pragma unroll
    for (int m = 0; m < 4; m++) {
        f32x4 v = se[m];
#pragma unroll
        for (int d = 1; d < 16; d <<= 1) {
            v[0] += __shfl_xor(v[0], d);
            v[1] += __shfl_xor(v[1], d);
            v[2] += __shfl_xor(v[2], d);
            v[3] += __shfl_xor(v[3], d);
        }
        if (l15 == 0) {
            float* p = parts + (size_t)(vc * 4 + cg) * 6016 + row0 + m * 16 + q * 4;
            p[0] = v[0]; p[1] = v[1]; p[2] = v[2]; p[3] = v[3];
        }
    }
}

// ---------------- final reduction ----------------
__global__ void k_final(const float* __restrict__ parts, const float* __restrict__ tl,
                        float* __restrict__ out) {
    __shared__ float red[1024];
    int tid = threadIdx.x;
    float acc = 0.f;
    for (int r = tid; r < 6016; r += 1024) {
        float tot = 0.f;
        for (int c = 0; c < 80; c++) tot += parts[(size_t)c * 6016 + r];
        acc += logf(tot) - tl[r];
    }
    red[tid] = acc;
    __syncthreads();
    for (int s = 512; s > 0; s >>= 1) {
        if (tid < s) red[tid] += red[tid + s];
        __syncthreads();
    }
    if (tid == 0) out[0] = red[0] / 6016.f;
}

extern "C" void kernel_launch(void* const* d_in, const int* in_sizes, int n_in,
                              void* d_out, int out_size, void* d_ws, size_t ws_size,
                              hipStream_t stream) {
    const int* doc = (const int*)d_in[0];
    const float* enc_emb = (const float*)d_in[1];
    const float* enc_Wih = (const float*)d_in[2];
    const float* enc_Whh = (const float*)d_in[3];
    const float* enc_bih = (const float*)d_in[4];
    const float* enc_bhh = (const float*)d_in[5];
    const float* doc_Wih = (const float*)d_in[6];
    const float* doc_Whh = (const float*)d_in[7];
    const float* doc_bih = (const float*)d_in[8];
    const float* doc_bhh = (const float*)d_in[9];
    const float* dec_emb = (const float*)d_in[10];
    const float* dec_Wih = (const float*)d_in[11];
    const float* dec_Whh = (const float*)d_in[12];
    const float* dec_bih = (const float*)d_in[13];
    const float* dec_bhh = (const float*)d_in[14];
    const float* fc_W = (const float*)d_in[15];
    const float* fc_b = (const float*)d_in[16];

    char* ws = (char*)d_ws;
    ushort_t* fcWb = (ushort_t*)(ws + 0);            // 8,192,000 B
    float* sent    = (float*)(ws + 8192000);         // 65,536 B
    float* dvec    = (float*)(ws + 8257536);         // 512 B
    float* gidoc   = (float*)(ws + 8258048);         // 196,608 B
    float* gctx    = (float*)(ws + 8454656);         // 1,536 B
    float* gidec   = (float*)(ws + 8456192);         // 9,240,576 B
    ushort_t* h2b  = (ushort_t*)(ws + 17696768);     // 1,540,096 B
    float* tl      = (float*)(ws + 19236864);        // 24,064 B
    float* parts   = (float*)(ws + 19260928);        // 80*6016*4 = 1,925,120 B
    float* out = (float*)d_out;

    k_convert<<<4000, 256, 0, stream>>>(fc_W, fcWb, 1024000);
    k_encoder<<<128, 384, 0, stream>>>(doc, enc_emb, enc_Wih, enc_Whh, enc_bih, enc_bhh, sent);
    k_doc_gi<<<128, 384, 0, stream>>>(sent, doc_Wih, doc_bih, gidoc);
    k_doc_seq<<<1, 384, 0, stream>>>(gidoc, doc_Whh, doc_bhh, dvec);
    k_gctx<<<1, 384, 0, stream>>>(dec_Wih, dec_bih, dvec, gctx);
    k_dec_gi<<<128, 384, 0, stream>>>(doc, dec_emb, dec_Wih, gctx, gidec);
    k_dec_seq<<<128, 384, 0, stream>>>(gidec, dec_Whh, dec_bhh, sent, h2b);
    k_tl<<<1504, 256, 0, stream>>>(doc, h2b, fcWb, fc_b, tl);
    k_lse<<<47 * LSE_VC, 512, 0, stream>>>(h2b, fcWb, fc_b, parts);
    k_final<<<1, 1024, 0, stream>>>(parts, tl, out);
}

// Round 4
// 345.691 us; speedup vs baseline: 2.3099x; 1.4737x over previous
//
#include <hip/hip_runtime.h>

typedef unsigned short ushort_t;
typedef short bf16x8 __attribute__((ext_vector_type(8)));
typedef float f32x4 __attribute__((ext_vector_type(4)));

__device__ __forceinline__ float bf2f(ushort_t u) {
    union { unsigned int i; float f; } v; v.i = ((unsigned int)u) << 16; return v.f;
}
__device__ __forceinline__ ushort_t f2bf(float f) {
    union { float f; unsigned int i; } v; v.f = f;
    unsigned int u = v.i;
    unsigned int r = (u + 0x7FFFu + ((u >> 16) & 1u)) >> 16;
    return (ushort_t)r;
}
__device__ __forceinline__ float hsum4(f32x4 v) { return (v[0] + v[1]) + (v[2] + v[3]); }

// ---------------- fc_W -> bf16 (vectorized) ----------------
__global__ void k_convert(const float* __restrict__ w, ushort_t* __restrict__ o, int n4) {
    int i = blockIdx.x * blockDim.x + threadIdx.x;
    if (i < n4) {
        f32x4 v = ((const f32x4*)w)[i];
        ushort_t r0 = f2bf(v[0]), r1 = f2bf(v[1]), r2 = f2bf(v[2]), r3 = f2bf(v[3]);
        union { ushort_t u[4]; unsigned long long q; } p;
        p.u[0] = r0; p.u[1] = r1; p.u[2] = r2; p.u[3] = r3;
        ((unsigned long long*)o)[i] = p.q;
    }
}

// ---------------- encoder GRU: one block per sentence s ----------------
__global__ __launch_bounds__(384, 1) void k_encoder(
    const int* __restrict__ doc, const float* __restrict__ emb,
    const float* __restrict__ Wih, const float* __restrict__ Whh,
    const float* __restrict__ bih, const float* __restrict__ bhh,
    float* __restrict__ sent) {
    int s = blockIdx.x, j = threadIdx.x;
    __shared__ f32x4 x4[16], h4[32];
    __shared__ float gi[384], gh[384];
    float* x = (float*)x4;
    float* h = (float*)h4;
    f32x4 wih[16], whh[32];
#pragma unroll
    for (int k = 0; k < 16; k++) wih[k] = *(const f32x4*)(Wih + j * 64 + k * 4);
#pragma unroll
    for (int k = 0; k < 32; k++) whh[k] = *(const f32x4*)(Whh + j * 128 + k * 4);
    float bi = bih[j], bh = bhh[j];
    if (j < 128) h[j] = 0.f;
    __syncthreads();
    for (int t = 0; t < 48; t++) {
        if (j < 64) { int tok = doc[s * 48 + t]; x[j] = emb[tok * 64 + j]; }
        __syncthreads();
        f32x4 a0 = {0,0,0,0}, a1 = {0,0,0,0}, b0 = {0,0,0,0}, b1 = {0,0,0,0};
#pragma unroll
        for (int k = 0; k < 16; k += 2) { a0 += wih[k] * x4[k]; a1 += wih[k+1] * x4[k+1]; }
#pragma unroll
        for (int k = 0; k < 32; k += 2) { b0 += whh[k] * h4[k]; b1 += whh[k+1] * h4[k+1]; }
        gi[j] = bi + hsum4(a0 + a1); gh[j] = bh + hsum4(b0 + b1);
        __syncthreads();
        if (j < 128) {
            float r = 1.f / (1.f + __expf(-(gi[j] + gh[j])));
            float z = 1.f / (1.f + __expf(-(gi[j + 128] + gh[j + 128])));
            float n = tanhf(gi[j + 256] + r * gh[j + 256]);
            h[j] = (1.f - z) * n + z * h[j];
        }
        __syncthreads();
    }
    if (j < 128) sent[s * 128 + j] = h[j];
}

// ---------------- doc-GRU input gates (parallel over steps) ----------------
__global__ void k_doc_gi(const float* __restrict__ sv, const float* __restrict__ Wih,
                         const float* __restrict__ bih, float* __restrict__ gidoc) {
    int i = blockIdx.x, j = threadIdx.x;
    __shared__ f32x4 v4[32];
    if (j < 128) ((float*)v4)[j] = sv[i * 128 + j];
    __syncthreads();
    f32x4 a0 = {0,0,0,0}, a1 = {0,0,0,0};
#pragma unroll
    for (int k = 0; k < 32; k += 2) {
        a0 += *(const f32x4*)(Wih + j * 128 + k * 4) * v4[k];
        a1 += *(const f32x4*)(Wih + j * 128 + (k + 1) * 4) * v4[k + 1];
    }
    gidoc[i * 384 + j] = bih[j] + hsum4(a0 + a1);
}

// ---------------- doc GRU: single block, 128 sequential steps ----------------
__global__ __launch_bounds__(384, 1) void k_doc_seq(
    const float* __restrict__ gidoc, const float* __restrict__ Whh,
    const float* __restrict__ bhh, float* __restrict__ dvec) {
    int j = threadIdx.x;
    __shared__ f32x4 h4[32];
    __shared__ float gi[384], gh[384];
    float* h = (float*)h4;
    f32x4 whh[32];
#pragma unroll
    for (int k = 0; k < 32; k++) whh[k] = *(const f32x4*)(Whh + j * 128 + k * 4);
    float bh = bhh[j];
    if (j < 128) h[j] = 0.f;
    __syncthreads();
    for (int i = 0; i < 128; i++) {
        float gval = gidoc[i * 384 + j];
        f32x4 b0 = {0,0,0,0}, b1 = {0,0,0,0};
#pragma unroll
        for (int k = 0; k < 32; k += 2) { b0 += whh[k] * h4[k]; b1 += whh[k+1] * h4[k+1]; }
        gh[j] = bh + hsum4(b0 + b1); gi[j] = gval;
        __syncthreads();
        if (j < 128) {
            float r = 1.f / (1.f + __expf(-(gi[j] + gh[j])));
            float z = 1.f / (1.f + __expf(-(gi[j + 128] + gh[j + 128])));
            float n = tanhf(gi[j + 256] + r * gh[j + 256]);
            h[j] = (1.f - z) * n + z * h[j];
        }
        __syncthreads();
    }
    if (j < 128) dvec[j] = h[j];
}

// ---------------- decoder context gate vector ----------------
__global__ void k_gctx(const float* __restrict__ Wih, const float* __restrict__ bih,
                       const float* __restrict__ dvec, float* __restrict__ gctx) {
    int j = threadIdx.x;
    __shared__ f32x4 v4[32];
    if (j < 128) ((float*)v4)[j] = dvec[j];
    __syncthreads();
    f32x4 a0 = {0,0,0,0}, a1 = {0,0,0,0};
#pragma unroll
    for (int k = 0; k < 32; k += 2) {
        a0 += *(const f32x4*)(Wih + j * 192 + 64 + k * 4) * v4[k];
        a1 += *(const f32x4*)(Wih + j * 192 + 64 + (k + 1) * 4) * v4[k + 1];
    }
    gctx[j] = bih[j] + hsum4(a0 + a1);
}

// ---------------- decoder input gates (parallel over s,t) ----------------
__global__ __launch_bounds__(384, 1) void k_dec_gi(
    const int* __restrict__ doc, const float* __restrict__ emb,
    const float* __restrict__ Wih, const float* __restrict__ gctx,
    float* __restrict__ gidec) {
    int s = blockIdx.x, j = threadIdx.x;
    __shared__ f32x4 x4[16];
    float* x = (float*)x4;
    f32x4 wih[16];
#pragma unroll
    for (int k = 0; k < 16; k++) wih[k] = *(const f32x4*)(Wih + j * 192 + k * 4);
    float g = gctx[j];
    for (int t = 0; t < 47; t++) {
        __syncthreads();
        if (j < 64) { int tok = doc[s * 48 + t]; x[j] = emb[tok * 64 + j]; }
        __syncthreads();
        f32x4 a0 = {0,0,0,0}, a1 = {0,0,0,0};
#pragma unroll
        for (int k = 0; k < 16; k += 2) { a0 += wih[k] * x4[k]; a1 += wih[k+1] * x4[k+1]; }
        gidec[(t * 128 + s) * 384 + j] = g + hsum4(a0 + a1);
    }
}

// ---------------- decoder GRU: one block per sentence, stores h2 (bf16) ----------------
__global__ __launch_bounds__(384, 1) void k_dec_seq(
    const float* __restrict__ gidec, const float* __restrict__ Whh,
    const float* __restrict__ bhh, const float* __restrict__ sent,
    ushort_t* __restrict__ h2b) {
    int s = blockIdx.x, j = threadIdx.x;
    __shared__ f32x4 h4[32];
    __shared__ float gi[384], gh[384];
    float* h = (float*)h4;
    f32x4 whh[32];
#pragma unroll
    for (int k = 0; k < 32; k++) whh[k] = *(const f32x4*)(Whh + j * 128 + k * 4);
    float bh = bhh[j];
    if (j < 128) h[j] = sent[s * 128 + j];
    __syncthreads();
    for (int t = 0; t < 47; t++) {
        float gval = gidec[(t * 128 + s) * 384 + j];
        f32x4 b0 = {0,0,0,0}, b1 = {0,0,0,0};
#pragma unroll
        for (int k = 0; k < 32; k += 2) { b0 += whh[k] * h4[k]; b1 += whh[k+1] * h4[k+1]; }
        gh[j] = bh + hsum4(b0 + b1); gi[j] = gval;
        __syncthreads();
        if (j < 128) {
            float r = 1.f / (1.f + __expf(-(gi[j] + gh[j])));
            float z = 1.f / (1.f + __expf(-(gi[j + 128] + gh[j + 128])));
            float n = tanhf(gi[j + 256] + r * gh[j + 256]);
            float hn = (1.f - z) * n + z * h[j];
            h[j] = hn;
            h2b[(t * 128 + s) * 128 + j] = f2bf(hn);
        }
        __syncthreads();
    }
}

// ---------------- target logits (one wave per row) ----------------
__global__ void k_tl(const int* __restrict__ doc, const ushort_t* __restrict__ h2b,
                     const ushort_t* __restrict__ wb, const float* __restrict__ fcb,
                     float* __restrict__ tl) {
    int r = blockIdx.x * 4 + (threadIdx.x >> 6);
    int lane = threadIdx.x & 63;
    int s = r & 127, t = r >> 7;
    int tok = doc[s * 48 + t + 1];
    const ushort_t* hp = h2b + r * 128;
    const ushort_t* wp = wb + tok * 128;
    float acc = bf2f(hp[lane]) * bf2f(wp[lane]) + bf2f(hp[lane + 64]) * bf2f(wp[lane + 64]);
#pragma unroll
    for (int m = 32; m >= 1; m >>= 1) acc += __shfl_xor(acc, m);
    if (lane == 0) tl[r] = acc + fcb[tok];
}

// ---------------- fused logits GEMM + sum(exp), LDS-staged 2-phase pipeline ----------------
// grid: 47 rowblocks x 20 v-chunks (1600 cols each, 25 tiles of 64).
// block 512 = 8 waves: 4 row-groups x 2 col-groups; wave computes 32 rows x 32 cols/tile.
// Register budget deliberately small (~85: a=32, acc=16, se=8) — rounds 2/3 proved
// the 64-rows/wave variant (a=64) spills its accumulators at any reachable VGPR cap.
#define LSE_VC 20
#define LSE_NC 1600
#define LSE_NT 25
__global__ __launch_bounds__(512, 2) void k_lse(
    const ushort_t* __restrict__ h2b, const ushort_t* __restrict__ wb,
    const float* __restrict__ fcb, float* __restrict__ parts) {
    int rb = blockIdx.x / LSE_VC;
    int vc = blockIdx.x % LSE_VC;
    int t = threadIdx.x;
    int wave = t >> 6, lane = t & 63;
    int rg = wave >> 1, cg = wave & 1;
    int q = lane >> 4, l15 = lane & 15;

    __shared__ __align__(16) char ldsB[32768];  // 2 x 16KB B tile

    // A fragments: 32 rows x K=128 per wave, register-resident (32 VGPRs)
    int row0 = rb * 128 + rg * 32;
    bf16x8 a[2][4];
    const ushort_t* ap = h2b + (size_t)(row0 + l15) * 128 + q * 8;
#pragma unroll
    for (int m = 0; m < 2; m++)
#pragma unroll
        for (int c = 0; c < 4; c++) a[m][c] = *(const bf16x8*)(ap + m * 2048 + c * 32);

    // staging: source offset inverse-swizzled, LDS dest linear (rule #21 pair)
    const char* wbB = (const char*)wb;
    int so = ((t >> 4) << 8) + (((t & 15) ^ ((t >> 4) & 15)) << 4);
    char* dst1 = ldsB + wave * 1024;

#define LSE_STAGE(buf, cb) do { \
    const char* g_ = wbB + (size_t)(cb) * 256 + so; \
    char* d_ = dst1 + (buf) * 16384; \
    __builtin_amdgcn_global_load_lds((const __attribute__((address_space(1))) unsigned int*)(g_), \
                                     (__attribute__((address_space(3))) unsigned int*)(d_), 16, 0, 0); \
    __builtin_amdgcn_global_load_lds((const __attribute__((address_space(1))) unsigned int*)(g_ + 8192), \
                                     (__attribute__((address_space(3))) unsigned int*)(d_ + 8192), 16, 0, 0); \
} while (0)

    // swizzled read offsets: chunk = cg*32 + c2*16 + l15, unit = (q+4c)^l15
    int ra[2][4];
#pragma unroll
    for (int c2 = 0; c2 < 2; c2++)
#pragma unroll
        for (int c = 0; c < 4; c++)
            ra[c2][c] = (cg * 32 + c2 * 16 + l15) * 256 + (((q + 4 * c) ^ l15) << 4);

    int cb0 = vc * LSE_NC;
    f32x4 se[2] = {{0,0,0,0},{0,0,0,0}};

    LSE_STAGE(0, cb0);
    __syncthreads();
    int cur = 0;
    for (int tile = 0; tile < LSE_NT; ++tile) {
        if (tile + 1 < LSE_NT) LSE_STAGE(cur ^ 1, cb0 + (tile + 1) * 64);
        const char* bb = ldsB + (cur << 14);
        int colg = cb0 + tile * 64 + cg * 32 + l15;
        float bias0 = fcb[colg], bias1 = fcb[colg + 16];
        f32x4 acc[2][2] = {{{0,0,0,0},{0,0,0,0}},{{0,0,0,0},{0,0,0,0}}};
#pragma unroll
        for (int c = 0; c < 4; c++) {
            bf16x8 b0 = *(const bf16x8*)(bb + ra[0][c]);
            bf16x8 b1 = *(const bf16x8*)(bb + ra[1][c]);
            acc[0][0] = __builtin_amdgcn_mfma_f32_16x16x32_bf16(a[0][c], b0, acc[0][0], 0, 0, 0);
            acc[1][0] = __builtin_amdgcn_mfma_f32_16x16x32_bf16(a[1][c], b0, acc[1][0], 0, 0, 0);
            acc[0][1] = __builtin_amdgcn_mfma_f32_16x16x32_bf16(a[0][c], b1, acc[0][1], 0, 0, 0);
            acc[1][1] = __builtin_amdgcn_mfma_f32_16x16x32_bf16(a[1][c], b1, acc[1][1], 0, 0, 0);
        }
#pragma unroll
        for (int m = 0; m < 2; m++) {
#pragma unroll
            for (int r = 0; r < 4; r++)
                se[m][r] += __expf(acc[m][0][r] + bias0) + __expf(acc[m][1][r] + bias1);
        }
        __syncthreads();
        cur ^= 1;
    }

    // reduce the 16 col-lanes; store one partial per (vc,cg) chunk (40 chunks total)
#pragma unroll
    for (int m = 0; m < 2; m++) {
        f32x4 v = se[m];
#pragma unroll
        for (int d = 1; d < 16; d <<= 1) {
            v[0] += __shfl_xor(v[0], d);
            v[1] += __shfl_xor(v[1], d);
            v[2] += __shfl_xor(v[2], d);
            v[3] += __shfl_xor(v[3], d);
        }
        if (l15 == 0) {
            float* p = parts + (size_t)(vc * 2 + cg) * 6016 + row0 + m * 16 + q * 4;
            p[0] = v[0]; p[1] = v[1]; p[2] = v[2]; p[3] = v[3];
        }
    }
}

// ---------------- per-row loss: logsumexp - target logit ----------------
__global__ void k_final1(const float* __restrict__ parts, const float* __restrict__ tl,
                         float* __restrict__ rowloss) {
    int r = blockIdx.x * 128 + threadIdx.x;
    float tot = 0.f;
#pragma unroll 8
    for (int c = 0; c < 40; c++) tot += parts[(size_t)c * 6016 + r];
    rowloss[r] = logf(tot) - tl[r];
}

// ---------------- final mean ----------------
__global__ void k_final2(const float* __restrict__ rowloss, float* __restrict__ out) {
    __shared__ float red[512];
    int tid = threadIdx.x;
    float acc = 0.f;
    for (int r = tid; r < 6016; r += 512) acc += rowloss[r];
    red[tid] = acc;
    __syncthreads();
    for (int s = 256; s > 0; s >>= 1) {
        if (tid < s) red[tid] += red[tid + s];
        __syncthreads();
    }
    if (tid == 0) out[0] = red[0] / 6016.f;
}

extern "C" void kernel_launch(void* const* d_in, const int* in_sizes, int n_in,
                              void* d_out, int out_size, void* d_ws, size_t ws_size,
                              hipStream_t stream) {
    const int* doc = (const int*)d_in[0];
    const float* enc_emb = (const float*)d_in[1];
    const float* enc_Wih = (const float*)d_in[2];
    const float* enc_Whh = (const float*)d_in[3];
    const float* enc_bih = (const float*)d_in[4];
    const float* enc_bhh = (const float*)d_in[5];
    const float* doc_Wih = (const float*)d_in[6];
    const float* doc_Whh = (const float*)d_in[7];
    const float* doc_bih = (const float*)d_in[8];
    const float* doc_bhh = (const float*)d_in[9];
    const float* dec_emb = (const float*)d_in[10];
    const float* dec_Wih = (const float*)d_in[11];
    const float* dec_Whh = (const float*)d_in[12];
    const float* dec_bih = (const float*)d_in[13];
    const float* dec_bhh = (const float*)d_in[14];
    const float* fc_W = (const float*)d_in[15];
    const float* fc_b = (const float*)d_in[16];

    char* ws = (char*)d_ws;
    ushort_t* fcWb = (ushort_t*)(ws + 0);            // 8,192,000 B
    float* sent    = (float*)(ws + 8192000);         // 65,536 B
    float* dvec    = (float*)(ws + 8257536);         // 512 B
    float* gidoc   = (float*)(ws + 8258048);         // 196,608 B
    float* gctx    = (float*)(ws + 8454656);         // 1,536 B
    float* gidec   = (float*)(ws + 8456192);         // 9,240,576 B
    ushort_t* h2b  = (ushort_t*)(ws + 17696768);     // 1,540,096 B
    float* tl      = (float*)(ws + 19236864);        // 24,064 B
    float* parts   = (float*)(ws + 19260928);        // 40*6016*4 = 962,560 B
    float* rowloss = (float*)(ws + 20223488);        // 24,064 B
    float* out = (float*)d_out;

    k_convert<<<4000, 256, 0, stream>>>(fc_W, fcWb, 1024000);
    k_encoder<<<128, 384, 0, stream>>>(doc, enc_emb, enc_Wih, enc_Whh, enc_bih, enc_bhh, sent);
    k_doc_gi<<<128, 384, 0, stream>>>(sent, doc_Wih, doc_bih, gidoc);
    k_doc_seq<<<1, 384, 0, stream>>>(gidoc, doc_Whh, doc_bhh, dvec);
    k_gctx<<<1, 384, 0, stream>>>(dec_Wih, dec_bih, dvec, gctx);
    k_dec_gi<<<128, 384, 0, stream>>>(doc, dec_emb, dec_Wih, gctx, gidec);
    k_dec_seq<<<128, 384, 0, stream>>>(gidec, dec_Whh, dec_bhh, sent, h2b);
    k_tl<<<1504, 256, 0, stream>>>(doc, h2b, fcWb, fc_b, tl);
    k_lse<<<47 * LSE_VC, 512, 0, stream>>>(h2b, fcWb, fc_b, parts);
    k_final1<<<47, 128, 0, stream>>>(parts, tl, rowloss);
    k_final2<<<1, 512, 0, stream>>>(rowloss, out);
}